// Round 6
// baseline (792.011 us; speedup 1.0000x reference)
//
#include <hip/hip_runtime.h>

#define CH 256
#define KC 8192
#define NT 32768

#define TM 128         // tokens per block
#define TN 128         // codes per jt tile
#define BK 32          // channels staged per stage
#define YS 4           // code quarters (grid.y)
#define JQ (KC / YS)   // 2048 codes per block
#define NSTG ((JQ / TN) * (CH / BK))   // 16 jt * 8 c0 = 128 stages

typedef _Float16 half4_t __attribute__((ext_vector_type(4)));
typedef _Float16 half8_t __attribute__((ext_vector_type(8)));
typedef float floatx4 __attribute__((ext_vector_type(4)));

typedef __attribute__((address_space(1))) const unsigned int guint_t;
typedef __attribute__((address_space(3))) unsigned int luint_t;

// XOR-swizzled LDS offset (halves) for row-major [row][BK] tiles, 16B chunks.
__device__ __forceinline__ int swz(int row, int chunk) {
    return row * BK + ((chunk ^ ((row >> 1) & 3)) << 3);
}

// ---------------------------------------------------------------------------
// Kernel 1 (fused prep):
//  blocks [0, KC):  codebook row -> fp16 hi/lo + cbsq, zero hist, init packed
//  blocks [KC, ..): split embeddings fp32 -> fp16 hi/lo (1 float4/thread)
// ---------------------------------------------------------------------------
__global__ void k_prep(const float* __restrict__ usage,
                       const float* __restrict__ ces,
                       const float* __restrict__ emb,
                       _Float16* __restrict__ cbh,
                       _Float16* __restrict__ cbl,
                       float* __restrict__ cbsq,
                       _Float16* __restrict__ eh,
                       _Float16* __restrict__ el,
                       int* __restrict__ hist,
                       unsigned long long* __restrict__ packed) {
    int b = blockIdx.x, t = threadIdx.x;
    if (b < KC) {
        float uc = fmaxf(usage[b], 1e-5f);
        float v  = ces[b * CH + t];
        float cb = v / uc;
        _Float16 h = (_Float16)cb;
        cbh[b * CH + t] = h;
        cbl[b * CH + t] = (_Float16)(cb - (float)h);

        float p = cb * cb;
        #pragma unroll
        for (int off = 32; off; off >>= 1) p += __shfl_down(p, off);
        __shared__ float ps[4];
        int lane = t & 63, w = t >> 6;
        if (lane == 0) ps[w] = p;
        __syncthreads();
        if (t == 0) cbsq[b] = ps[0] + ps[1] + ps[2] + ps[3];
        if (t == 1) hist[b] = 0;
        int gid = b * CH + t;
        if (gid < NT) packed[gid] = 0xFFFFFFFFFFFFFFFFull;
    } else {
        int i = (b - KC) * 256 + t;      // float4 index
        float4 v = ((const float4*)emb)[i];
        float va[4] = {v.x, v.y, v.z, v.w};
        half4_t h, l;
        #pragma unroll
        for (int q = 0; q < 4; ++q) {
            _Float16 hh = (_Float16)va[q];
            h[q] = hh;
            l[q] = (_Float16)(va[q] - (float)hh);
        }
        ((half4_t*)eh)[i] = h;
        ((half4_t*)el)[i] = l;
    }
}

// ---------------------------------------------------------------------------
// Kernel 2: fp16-split MFMA argmin.
// Single 32KB LDS buffer via global_load_lds DMA (no staging VGPRs).
// Running argmin lives in an LDS candidate table (updated at each jt fold
// after an in-wave shuffle reduce) -> no per-thread min registers ->
// arch+acc fits 128 regs -> 4 blocks/CU.
// ---------------------------------------------------------------------------
__launch_bounds__(256, 4)
__global__ void k_argmin(const _Float16* __restrict__ eh,
                         const _Float16* __restrict__ el,
                         const _Float16* __restrict__ cbh,
                         const _Float16* __restrict__ cbl,
                         const float* __restrict__ cbsq,
                         unsigned long long* __restrict__ packed) {
    __shared__ __align__(16) _Float16 sm[4][TM * BK];   // 32 KiB
    __shared__ float cand_v[2][TM];
    __shared__ int   cand_i[2][TM];

    const int t    = threadIdx.x;
    const int lane = t & 63;
    const int wave = t >> 6;
    const int wx   = wave & 1;        // code half (64 codes)
    const int wy   = wave >> 1;       // token half (64 tokens)
    const int lr   = lane & 15;
    const int koq  = lane >> 4;       // k-chunk (quad) for fragments

    const int n0 = blockIdx.x * TM;
    const int jq = blockIdx.y * JQ;

    // DMA assignment: wave w stages array w of {Ah,Al,Bh,Bl}; lane->chunk
    // pre-applies the XOR swizzle (inverse): q = (lane&3) ^ ((lane>>3)&3).
    const _Float16* dsrc = (wave == 0) ? eh : (wave == 1) ? el
                         : (wave == 2) ? cbh : cbl;
    const int qsw  = (lane & 3) ^ ((lane >> 3) & 3);
    const int lrow = lane >> 2;

    if (t < TM) {
        cand_v[0][t] = 3.402823466e38f; cand_i[0][t] = 0;
        cand_v[1][t] = 3.402823466e38f; cand_i[1][t] = 0;
    }

    floatx4 acc[4][4];
    #pragma unroll
    for (int mf = 0; mf < 4; ++mf)
        #pragma unroll
        for (int nf = 0; nf < 4; ++nf)
            acc[mf][nf] = (floatx4){0.f, 0.f, 0.f, 0.f};

    #pragma unroll 1
    for (int s = 0; s < NSTG; ++s) {
        const int c0 = (s & 7) * BK;
        const int jb = jq + (s >> 3) * TN;
        const int rb = (wave < 2) ? n0 : jb;

        // ---- DMA stage s into LDS (8 x 1KB per wave) ----
        {
            const _Float16* gbase = dsrc + (size_t)(rb + lrow) * CH + c0 + qsw * 8;
            #pragma unroll
            for (int i = 0; i < 8; ++i) {
                const _Float16* g = gbase + (size_t)(i * 16) * CH;
                __builtin_amdgcn_global_load_lds(
                    (guint_t*)g, (luint_t*)&sm[wave][i * 512], 16, 0, 0);
            }
        }
        __syncthreads();   // drains vmcnt: stage s visible to all waves

        // ---- fragments + MFMA ----
        half8_t fah[4], fal[4];
        #pragma unroll
        for (int mf = 0; mf < 4; ++mf) {
            int off = swz(wy * 64 + mf * 16 + lr, koq);
            fah[mf] = *(const half8_t*)&sm[0][off];
            fal[mf] = *(const half8_t*)&sm[1][off];
        }
        #pragma unroll
        for (int nf = 0; nf < 4; ++nf) {
            int offb = swz(wx * 64 + nf * 16 + lr, koq);
            half8_t fbh = *(const half8_t*)&sm[2][offb];
            half8_t fbl = *(const half8_t*)&sm[3][offb];
            #pragma unroll
            for (int mf = 0; mf < 4; ++mf) {
                acc[mf][nf] = __builtin_amdgcn_mfma_f32_16x16x32_f16(
                    fah[mf], fbh, acc[mf][nf], 0, 0, 0);
                acc[mf][nf] = __builtin_amdgcn_mfma_f32_16x16x32_f16(
                    fah[mf], fbl, acc[mf][nf], 0, 0, 0);
                acc[mf][nf] = __builtin_amdgcn_mfma_f32_16x16x32_f16(
                    fal[mf], fbh, acc[mf][nf], 0, 0, 0);
            }
        }

        if ((s & 7) == 7) {
            // ---- fold the finished 128-code jt tile into the LDS table ----
            // C/D: col(code)=lr within nf*16, row(token)=koq*4+r within mf*16.
            // Process nf pairs (0,1),(2,3): combine in-reg (smaller j wins
            // ties since nf0's j < nf1's j), shuffle-reduce over lr, then one
            // predicated LDS compare-update (unique row owner -> no race).
            int jbase = jq + (s >> 3) * TN;
            #pragma unroll
            for (int np = 0; np < 2; ++np) {
                int j0 = jbase + wx * 64 + (np * 2) * 16 + lr;
                float sq0 = cbsq[j0];
                float sq1 = cbsq[j0 + 16];
                #pragma unroll
                for (int mf = 0; mf < 4; ++mf) {
                    #pragma unroll
                    for (int r = 0; r < 4; ++r) {
                        float v0 = sq0 - 2.0f * acc[mf][np * 2][r];
                        float v1 = sq1 - 2.0f * acc[mf][np * 2 + 1][r];
                        float v = v0; int x = j0;
                        if (v1 < v) { v = v1; x = j0 + 16; }
                        #pragma unroll
                        for (int m = 1; m <= 8; m <<= 1) {
                            float ov = __shfl_xor(v, m, 64);
                            int   ox = __shfl_xor(x, m, 64);
                            if (ov < v || (ov == v && ox < x)) { v = ov; x = ox; }
                        }
                        if (lr == 0) {
                            int row = wy * 64 + mf * 16 + koq * 4 + r;
                            float cv = cand_v[wx][row];
                            int   ci = cand_i[wx][row];
                            if (v < cv || (v == cv && x < ci)) {
                                cand_v[wx][row] = v;
                                cand_i[wx][row] = x;
                            }
                        }
                    }
                }
            }
            #pragma unroll
            for (int mf = 0; mf < 4; ++mf)
                #pragma unroll
                for (int nf = 0; nf < 4; ++nf)
                    acc[mf][nf] = (floatx4){0.f, 0.f, 0.f, 0.f};
        }
        __syncthreads();   // all LDS reads done before next stage's DMA
    }

    if (t < TM) {
        float v0 = cand_v[0][t]; int i0 = cand_i[0][t];
        float v1 = cand_v[1][t]; int i1 = cand_i[1][t];
        if (v1 < v0 || (v1 == v0 && i1 < i0)) { v0 = v1; i0 = i1; }
        unsigned sb = __float_as_uint(v0);
        sb = (sb & 0x80000000u) ? ~sb : (sb | 0x80000000u);
        unsigned long long key = ((unsigned long long)sb << 32) | (unsigned)i0;
        atomicMin(&packed[n0 + t], key);
    }
}

// ---------------------------------------------------------------------------
// Kernel 3: gather + straight-through + loss partials + histogram
// ---------------------------------------------------------------------------
__global__ void k_gather(const float* __restrict__ emb,
                         const float* __restrict__ ces,
                         const float* __restrict__ usage,
                         const unsigned long long* __restrict__ packed,
                         float* __restrict__ out_eq,
                         float* __restrict__ codes_f,
                         int* __restrict__ hist,
                         float* __restrict__ partials) {
    int t = threadIdx.x;
    int wave = t >> 6, lane = t & 63;
    int n = blockIdx.x * 4 + wave;
    int k = (int)(packed[n] & 0xFFFFFFFFull);
    float uc = fmaxf(usage[k], 1e-5f);
    int c = lane * 4;

    float4 e = *(const float4*)&emb[(size_t)n * CH + c];
    float4 v = *(const float4*)&ces[(size_t)k * CH + c];
    float ea[4] = {e.x, e.y, e.z, e.w};
    float va[4] = {v.x, v.y, v.z, v.w};
    float eqa[4];
    float p = 0.0f;
    #pragma unroll
    for (int q = 0; q < 4; ++q) {
        float cb = va[q] / uc;
        float eq = ea[q] + (cb - ea[q]);
        eqa[q] = eq;
        float d = eq - ea[q];
        p += d * d;
    }
    *(float4*)&out_eq[(size_t)n * CH + c] =
        (float4){eqa[0], eqa[1], eqa[2], eqa[3]};

    #pragma unroll
    for (int off = 32; off; off >>= 1) p += __shfl_down(p, off);
    __shared__ float ps[4];
    if (lane == 0) {
        ps[wave] = p;
        codes_f[n] = (float)k;
        atomicAdd(&hist[k], 1);
    }
    __syncthreads();
    if (t == 0) partials[blockIdx.x] = ps[0] + ps[1] + ps[2] + ps[3];
}

// ---------------------------------------------------------------------------
// Kernel 4: exclusive prefix sum over hist -> offs, cursor (1 block)
// ---------------------------------------------------------------------------
__global__ void k_scan(const int* __restrict__ hist,
                       int* __restrict__ offs,
                       int* __restrict__ cursor) {
    __shared__ int bs[256];
    int t = threadIdx.x;
    int base = t * 32;
    int loc[32];
    int s = 0;
    #pragma unroll
    for (int i = 0; i < 32; ++i) { loc[i] = s; s += hist[base + i]; }
    int mysum = s;
    bs[t] = s;
    __syncthreads();
    for (int off = 1; off < 256; off <<= 1) {
        int v = (t >= off) ? bs[t - off] : 0;
        __syncthreads();
        bs[t] += v;
        __syncthreads();
    }
    int excl = bs[t] - mysum;
    #pragma unroll
    for (int i = 0; i < 32; ++i) {
        int o = excl + loc[i];
        offs[base + i]   = o;
        cursor[base + i] = o;
    }
}

// ---------------------------------------------------------------------------
// Kernel 5: scatter token ids into code-sorted buckets
// ---------------------------------------------------------------------------
__global__ void k_scatter(const unsigned long long* __restrict__ packed,
                          int* __restrict__ cursor,
                          int* __restrict__ bucket) {
    int n = blockIdx.x * 256 + threadIdx.x;
    int k = (int)(packed[n] & 0xFFFFFFFFull);
    int pos = atomicAdd(&cursor[k], 1);
    bucket[pos] = n;
}

// ---------------------------------------------------------------------------
// Kernel 6: per-code EMA (one block per code, no atomics). Block KC does the
// loss-partials reduction (partials were finished by k_gather).
// ---------------------------------------------------------------------------
__global__ void k_ema(const float* __restrict__ emb,
                      const float* __restrict__ ces,
                      const float* __restrict__ usage,
                      const int* __restrict__ hist,
                      const int* __restrict__ offs,
                      const int* __restrict__ bucket,
                      float* __restrict__ out_ces,
                      float* __restrict__ out_usage,
                      const float* __restrict__ partials,
                      float* __restrict__ out_loss) {
    int k = blockIdx.x, t = threadIdx.x;
    if (k == KC) {
        float p = 0.0f;
        for (int i = t; i < NT / 4; i += 256) p += partials[i];
        #pragma unroll
        for (int off = 32; off; off >>= 1) p += __shfl_down(p, off);
        __shared__ float ps[4];
        if ((t & 63) == 0) ps[t >> 6] = p;
        __syncthreads();
        if (t == 0)
            out_loss[0] = (ps[0] + ps[1] + ps[2] + ps[3]) * (1.0f / 8388608.0f);
        return;
    }
    const float s = 0.01f;
    const float oms = 1.0f - s;
    int start = offs[k], cnt = hist[k];
    float sum = 0.0f;
    #pragma unroll 2
    for (int i = 0; i < cnt; ++i) {
        int n = bucket[start + i];            // block-uniform load
        sum += emb[(size_t)n * CH + t];       // coalesced row
    }
    out_ces[(size_t)k * CH + t] = oms * ces[(size_t)k * CH + t] + s * sum;
    if (t == 0) out_usage[k] = oms * usage[k] + s * (float)cnt;
}

extern "C" void kernel_launch(void* const* d_in, const int* in_sizes, int n_in,
                              void* d_out, int out_size, void* d_ws, size_t ws_size,
                              hipStream_t stream) {
    const float* emb   = (const float*)d_in[0];  // [32768, 256]
    const float* usage = (const float*)d_in[1];  // [8192]
    const float* ces   = (const float*)d_in[2];  // [8192, 256]

    float* out      = (float*)d_out;
    float* o_codes  = out;                       // 32768
    float* o_eq     = out + NT;                  // 8388608
    float* o_loss   = o_eq + (size_t)NT * CH;    // 1
    float* o_usage  = o_loss + 1;                // 8192
    float* o_ces    = o_usage + KC;              // 2097152

    unsigned long long* packed = (unsigned long long*)d_ws;   // NT u64
    float* cbsq     = (float*)(packed + NT);                  // KC
    float* partials = cbsq + KC;                              // NT/4
    int* hist   = (int*)(partials + NT / 4);                  // KC
    int* offs   = hist + KC;                                  // KC
    int* cursor = offs + KC;                                  // KC
    int* bucket = cursor + KC;                                // NT
    _Float16* eh  = (_Float16*)(bucket + NT);                 // NT*CH
    _Float16* el  = eh + (size_t)NT * CH;
    _Float16* cbh = el + (size_t)NT * CH;                     // KC*CH
    _Float16* cbl = cbh + (size_t)KC * CH;

    k_prep<<<KC + NT * CH / 1024, 256, 0, stream>>>(
        usage, ces, emb, cbh, cbl, cbsq, eh, el, hist, packed);
    dim3 agrid(NT / TM, YS);
    k_argmin<<<agrid, 256, 0, stream>>>(eh, el, cbh, cbl, cbsq, packed);
    k_gather<<<NT / 4, 256, 0, stream>>>(emb, ces, usage, packed, o_eq,
                                         o_codes, hist, partials);
    k_scan<<<1, 256, 0, stream>>>(hist, offs, cursor);
    k_scatter<<<NT / 256, 256, 0, stream>>>(packed, cursor, bucket);
    k_ema<<<KC + 1, 256, 0, stream>>>(emb, ces, usage, hist, offs, bucket,
                                      o_ces, o_usage, partials, o_loss);
}